// Round 4
// baseline (70.130 us; speedup 1.0000x reference)
//
#include <hip/hip_runtime.h>

// Problem constants (from reference): B=4, C=64, G=64, P=8, S=G*P=512
constexpr int Bn = 4;
constexpr int Cn = 64;
constexpr int Gn = 64;
constexpr int Pn = 8;
constexpr int Sn = Gn * Pn;          // 512

constexpr int CPB   = 16;            // grid cells per block along x
constexpr int XSPAN = CPB * Pn;      // 128 output columns per block
constexpr int NXB   = Sn / XSPAN;    // 4 blocks along x
constexpr int COLS  = CPB + 2;       // 18 staged fea columns (with halo)
constexpr int CH    = 32;            // channels per block (channel-split)
constexpr int LDC   = 36;            // padded channel stride (float)

// out[b,c,y,x] = sum_{dy,dx} prob[b, 3*dy+dx, y, x] * fea[b, ch*G+cw, c]
//   ch = clamp(y/P + dy - 1), cw = clamp(x/P + dx - 1)
// R1/R3 proven mapping + channel-split (2 blocks cover the 64 channels) for
// 2048 blocks = 8/CU -> higher occupancy, finer tail.
__global__ __launch_bounds__(256, 4)
void sp_upsample_kernel(const float* __restrict__ fea,
                        const float* __restrict__ prob,
                        float* __restrict__ out) {
    __shared__ float fea_lds[3 * COLS * LDC];   // 7776 B

    const int bx    = blockIdx.x;
    const int cHalf = bx & 1;               // channel half (0..1)
    const int xb    = (bx >> 1) & (NXB - 1);// x-block (0..3)
    const int h     = (bx >> 3) & (Gn - 1); // grid row
    const int b     = bx >> 9;              // batch
    const int w0  = xb * CPB;               // first cell col
    const int x0  = xb * XSPAN;             // first output col
    const int tid = threadIdx.x;

    // ---- stage fea neighborhood: rows h-1..h+1 (clamped), cols w0-1..w0+16 (clamped)
    constexpr int NVEC = 3 * COLS * (CH / 4);   // 432 float4s
    for (int idx = tid; idx < NVEC; idx += 256) {
        const int c4   = idx & 7;           // channel group (0..7)
        const int colr = idx >> 3;
        const int col  = colr % COLS;
        const int r    = colr / COLS;
        const int gh = min(max(h - 1 + r, 0), Gn - 1);
        const int gw = min(max(w0 - 1 + col, 0), Gn - 1);
        const float4 v = *reinterpret_cast<const float4*>(
            fea + ((size_t)(b * Gn * Gn + gh * Gn + gw)) * Cn + cHalf * CH + c4 * 4);
        *reinterpret_cast<float4*>(&fea_lds[(r * COLS + col) * LDC + c4 * 4]) = v;
    }
    __syncthreads();

    // ---- thread mapping: 128 x-positions x 2 p1-quads; each thread: 4 rows, 32 ch
    const int xl   = tid & (XSPAN - 1);     // 0..127
    const int p1q  = tid >> 7;              // 0..1
    const int x    = x0 + xl;
    const int cell = xl >> 3;               // local cell 0..15
    const int ybase = h * Pn + p1q * 4;

    // load prob: 4 rows x 9 neighbors into registers (coalesced along x, streaming)
    float p[4][9];
    const size_t SS = (size_t)Sn * Sn;
    #pragma unroll
    for (int r = 0; r < 4; ++r) {
        const float* pb = prob + (size_t)b * 9 * SS + (size_t)(ybase + r) * Sn + x;
        #pragma unroll
        for (int k = 0; k < 9; ++k)
            p[r][k] = __builtin_nontemporal_load(pb + (size_t)k * SS);
    }

    float* ob = out + ((size_t)b * Cn + cHalf * CH) * SS;

    #pragma unroll 1
    for (int c4 = 0; c4 < CH / 4; ++c4) {
        // 9 neighbor fea float4s for this channel group (LDS broadcast)
        float4 f[9];
        #pragma unroll
        for (int k = 0; k < 9; ++k) {
            const int dy = k / 3, dx = k % 3;   // compile-time
            f[k] = *reinterpret_cast<const float4*>(
                &fea_lds[(dy * COLS + cell + dx) * LDC + c4 * 4]);
        }
        float4 acc[4];
        #pragma unroll
        for (int r = 0; r < 4; ++r) acc[r] = make_float4(0.f, 0.f, 0.f, 0.f);
        #pragma unroll
        for (int k = 0; k < 9; ++k) {
            #pragma unroll
            for (int r = 0; r < 4; ++r) {
                acc[r].x = fmaf(p[r][k], f[k].x, acc[r].x);
                acc[r].y = fmaf(p[r][k], f[k].y, acc[r].y);
                acc[r].z = fmaf(p[r][k], f[k].z, acc[r].z);
                acc[r].w = fmaf(p[r][k], f[k].w, acc[r].w);
            }
        }
        #pragma unroll
        for (int r = 0; r < 4; ++r) {
            const size_t base = (size_t)(c4 * 4) * SS + (size_t)(ybase + r) * Sn + x;
            __builtin_nontemporal_store(acc[r].x, ob + base);
            __builtin_nontemporal_store(acc[r].y, ob + base + SS);
            __builtin_nontemporal_store(acc[r].z, ob + base + 2 * SS);
            __builtin_nontemporal_store(acc[r].w, ob + base + 3 * SS);
        }
    }
}

extern "C" void kernel_launch(void* const* d_in, const int* in_sizes, int n_in,
                              void* d_out, int out_size, void* d_ws, size_t ws_size,
                              hipStream_t stream) {
    const float* fea  = (const float*)d_in[0];   // [4, 4096, 64]
    const float* prob = (const float*)d_in[1];   // [4, 9, 512, 512]
    float* out = (float*)d_out;                  // [4, 64, 512, 512]

    const int grid = Bn * Gn * NXB * 2;          // 2048 blocks
    sp_upsample_kernel<<<grid, 256, 0, stream>>>(fea, prob, out);
}

// Round 5
// 62.722 us; speedup vs baseline: 1.1181x; 1.1181x over previous
//
#include <hip/hip_runtime.h>

// Problem constants (from reference): B=4, C=64, G=64, P=8, S=G*P=512
constexpr int Bn = 4;
constexpr int Cn = 64;
constexpr int Gn = 64;
constexpr int Pn = 8;
constexpr int Sn = Gn * Pn;          // 512

constexpr int CPB   = 16;            // grid cells per block along x
constexpr int XSPAN = CPB * Pn;      // 128 output columns per block
constexpr int NXB   = Sn / XSPAN;    // 4 blocks along x
constexpr int COLS  = CPB + 2;       // 18 staged fea columns (with halo)
constexpr int LDC   = 68;            // padded channel stride (float)

// out[b,c,y,x] = sum_{dy,dx} prob[b, 3*dy+dx, y, x] * fea[b, ch*G+cw, c]
//   ch = clamp(y/P + dy - 1), cw = clamp(x/P + dx - 1)
// R3 kernel with relaxed launch bounds: (256,4) capped VGPR at 64 and forced
// scratch spills of the ~90-reg live set (p[4][9] + f[9] + acc). (256,2)
// allows ~128 VGPR -> no spill. Occupancy loss is irrelevant (R4 evidence).
__global__ __launch_bounds__(256, 2)
void sp_upsample_kernel(const float* __restrict__ fea,
                        const float* __restrict__ prob,
                        float* __restrict__ out) {
    __shared__ float fea_lds[3 * COLS * LDC];   // 14688 B

    const int bx  = blockIdx.x;
    const int xb  = bx & (NXB - 1);         // x-block (0..3)
    const int h   = (bx >> 2) & (Gn - 1);   // grid row
    const int b   = bx >> 8;                // batch
    const int w0  = xb * CPB;               // first cell col
    const int x0  = xb * XSPAN;             // first output col
    const int tid = threadIdx.x;

    // ---- stage fea neighborhood: rows h-1..h+1 (clamped), cols w0-1..w0+16 (clamped)
    constexpr int NVEC = 3 * COLS * (Cn / 4);   // 864 float4s
    for (int idx = tid; idx < NVEC; idx += 256) {
        const int c4   = idx & 15;          // channel group
        const int colr = idx >> 4;
        const int col  = colr % COLS;
        const int r    = colr / COLS;
        const int gh = min(max(h - 1 + r, 0), Gn - 1);
        const int gw = min(max(w0 - 1 + col, 0), Gn - 1);
        const float4 v = *reinterpret_cast<const float4*>(
            fea + ((size_t)(b * Gn * Gn + gh * Gn + gw)) * Cn + c4 * 4);
        *reinterpret_cast<float4*>(&fea_lds[(r * COLS + col) * LDC + c4 * 4]) = v;
    }
    __syncthreads();

    // ---- thread mapping: 128 x-positions x 2 p1-quads; each thread: 4 rows, all 64 ch
    const int xl   = tid & (XSPAN - 1);     // 0..127
    const int p1q  = tid >> 7;              // 0..1
    const int x    = x0 + xl;
    const int cell = xl >> 3;               // local cell 0..15
    const int ybase = h * Pn + p1q * 4;

    // load prob: 4 rows x 9 neighbors into registers (coalesced along x, streaming)
    float p[4][9];
    const size_t SS = (size_t)Sn * Sn;
    #pragma unroll
    for (int r = 0; r < 4; ++r) {
        const float* pb = prob + (size_t)b * 9 * SS + (size_t)(ybase + r) * Sn + x;
        #pragma unroll
        for (int k = 0; k < 9; ++k)
            p[r][k] = __builtin_nontemporal_load(pb + (size_t)k * SS);
    }

    float* ob = out + (size_t)b * Cn * SS;

    #pragma unroll 1
    for (int c4 = 0; c4 < Cn / 4; ++c4) {
        // 9 neighbor fea float4s for this channel group (LDS broadcast)
        float4 f[9];
        #pragma unroll
        for (int k = 0; k < 9; ++k) {
            const int dy = k / 3, dx = k % 3;   // compile-time
            f[k] = *reinterpret_cast<const float4*>(
                &fea_lds[(dy * COLS + cell + dx) * LDC + c4 * 4]);
        }
        float4 acc[4];
        #pragma unroll
        for (int r = 0; r < 4; ++r) acc[r] = make_float4(0.f, 0.f, 0.f, 0.f);
        #pragma unroll
        for (int k = 0; k < 9; ++k) {
            #pragma unroll
            for (int r = 0; r < 4; ++r) {
                acc[r].x = fmaf(p[r][k], f[k].x, acc[r].x);
                acc[r].y = fmaf(p[r][k], f[k].y, acc[r].y);
                acc[r].z = fmaf(p[r][k], f[k].z, acc[r].z);
                acc[r].w = fmaf(p[r][k], f[k].w, acc[r].w);
            }
        }
        #pragma unroll
        for (int r = 0; r < 4; ++r) {
            const size_t base = (size_t)(c4 * 4) * SS + (size_t)(ybase + r) * Sn + x;
            __builtin_nontemporal_store(acc[r].x, ob + base);
            __builtin_nontemporal_store(acc[r].y, ob + base + SS);
            __builtin_nontemporal_store(acc[r].z, ob + base + 2 * SS);
            __builtin_nontemporal_store(acc[r].w, ob + base + 3 * SS);
        }
    }
}

extern "C" void kernel_launch(void* const* d_in, const int* in_sizes, int n_in,
                              void* d_out, int out_size, void* d_ws, size_t ws_size,
                              hipStream_t stream) {
    const float* fea  = (const float*)d_in[0];   // [4, 4096, 64]
    const float* prob = (const float*)d_in[1];   // [4, 9, 512, 512]
    float* out = (float*)d_out;                  // [4, 64, 512, 512]

    const int grid = Bn * Gn * NXB;              // 1024 blocks
    sp_upsample_kernel<<<grid, 256, 0, stream>>>(fea, prob, out);
}

// Round 7
// 62.714 us; speedup vs baseline: 1.1183x; 1.0001x over previous
//
#include <hip/hip_runtime.h>

// Problem constants (from reference): B=4, C=64, G=64, P=8, S=G*P=512
constexpr int Bn = 4;
constexpr int Cn = 64;
constexpr int Gn = 64;
constexpr int Pn = 8;
constexpr int Sn = Gn * Pn;          // 512

constexpr int CPB   = 16;            // grid cells per block along x
constexpr int XSPAN = CPB * Pn;      // 128 output columns per block
constexpr int NXB   = Sn / XSPAN;    // 4 blocks along x
constexpr int COLS  = CPB + 2;       // 18 staged fea columns (with halo)
constexpr int LDC   = 68;            // padded channel stride (float)

// native vector type: __builtin_nontemporal_* requires it (HIP float4 is a class)
typedef float f32x4 __attribute__((ext_vector_type(4)));

// out[b,c,y,x] = sum_{dy,dx} prob[b, 3*dy+dx, y, x] * fea[b, ch*G+cw, c]
//   ch = clamp(y/P + dy - 1), cw = clamp(x/P + dx - 1)
// R2's float4-store mapping, de-confounded: __launch_bounds__(256,2) so the
// ~100-reg live set fits (R2's 175us was scratch-spill traffic from the
// VGPR=64 cap, not the mapping). Stores/loads are nontemporal dwordx4.
__global__ __launch_bounds__(256, 2)
void sp_upsample_kernel(const float* __restrict__ fea,
                        const float* __restrict__ prob,
                        float* __restrict__ out) {
    __shared__ float fea_lds[3 * COLS * LDC];   // 14688 B

    const int bx  = blockIdx.x;
    const int xb  = bx & (NXB - 1);         // x-block (0..3)
    const int h   = (bx >> 2) & (Gn - 1);   // grid row
    const int b   = bx >> 8;                // batch
    const int w0  = xb * CPB;               // first cell col
    const int x0  = xb * XSPAN;             // first output col
    const int tid = threadIdx.x;

    // ---- stage fea neighborhood: rows h-1..h+1 (clamped), cols w0-1..w0+16 (clamped)
    constexpr int NVEC = 3 * COLS * (Cn / 4);   // 864 float4s
    for (int idx = tid; idx < NVEC; idx += 256) {
        const int c4   = idx & 15;          // channel group
        const int colr = idx >> 4;
        const int col  = colr % COLS;
        const int r    = colr / COLS;
        const int gh = min(max(h - 1 + r, 0), Gn - 1);
        const int gw = min(max(w0 - 1 + col, 0), Gn - 1);
        const f32x4 v = *reinterpret_cast<const f32x4*>(
            fea + ((size_t)(b * Gn * Gn + gh * Gn + gw)) * Cn + c4 * 4);
        *reinterpret_cast<f32x4*>(&fea_lds[(r * COLS + col) * LDC + c4 * 4]) = v;
    }
    __syncthreads();

    // ---- thread mapping: tid = (row<<5)|xg ; 4 consecutive x, one row, 64 ch
    const int xg   = tid & 31;              // x-group (4 consecutive x)
    const int row  = tid >> 5;              // 0..7
    const int x    = x0 + xg * 4;
    const int cell = xg >> 1;               // local cell 0..15
    const int y    = h * Pn + row;

    const size_t SS = (size_t)Sn * Sn;
    const size_t yoff = (size_t)y * Sn + x;

    // load prob: 9 neighbors x 4 x-positions (dwordx4, streaming)
    f32x4 p[9];
    const float* pb = prob + (size_t)b * 9 * SS + yoff;
    #pragma unroll
    for (int k = 0; k < 9; ++k)
        p[k] = __builtin_nontemporal_load(
            reinterpret_cast<const f32x4*>(pb + (size_t)k * SS));

    float* ob = out + (size_t)b * Cn * SS + yoff;

    #pragma unroll 1
    for (int c4 = 0; c4 < Cn / 4; ++c4) {
        // 9 neighbor fea float4s for this channel group (LDS, <=2-way conflict)
        f32x4 f[9];
        #pragma unroll
        for (int k = 0; k < 9; ++k) {
            const int dy = k / 3, dx = k % 3;   // compile-time
            f[k] = *reinterpret_cast<const f32x4*>(
                &fea_lds[(dy * COLS + cell + dx) * LDC + c4 * 4]);
        }
        // acc[j] = f32x4 over 4 x-positions for channel c4*4+j
        f32x4 acc[4];
        #pragma unroll
        for (int j = 0; j < 4; ++j) acc[j] = (f32x4)(0.f);
        #pragma unroll
        for (int k = 0; k < 9; ++k) {
            const f32x4 fk = f[k];
            const f32x4 pk = p[k];
            #pragma unroll
            for (int j = 0; j < 4; ++j) {
                acc[j].x = fmaf(pk.x, fk[j], acc[j].x);
                acc[j].y = fmaf(pk.y, fk[j], acc[j].y);
                acc[j].z = fmaf(pk.z, fk[j], acc[j].z);
                acc[j].w = fmaf(pk.w, fk[j], acc[j].w);
            }
        }
        #pragma unroll
        for (int j = 0; j < 4; ++j)
            __builtin_nontemporal_store(acc[j],
                reinterpret_cast<f32x4*>(ob + (size_t)(c4 * 4 + j) * SS));
    }
}

extern "C" void kernel_launch(void* const* d_in, const int* in_sizes, int n_in,
                              void* d_out, int out_size, void* d_ws, size_t ws_size,
                              hipStream_t stream) {
    const float* fea  = (const float*)d_in[0];   // [4, 4096, 64]
    const float* prob = (const float*)d_in[1];   // [4, 9, 512, 512]
    float* out = (float*)d_out;                  // [4, 64, 512, 512]

    const int grid = Bn * Gn * NXB;              // 1024 blocks
    sp_upsample_kernel<<<grid, 256, 0, stream>>>(fea, prob, out);
}